// Round 3
// baseline (532.190 us; speedup 1.0000x reference)
//
#include <hip/hip_runtime.h>
#include <cstddef>
#include <cstdint>

#define B 256
#define N 2048
#define DH 128
#define DG 256
#define HID 256
#define WAVES 8
#define TPB (WAVES * 64)     // 512 threads, 8 waves, 1 block per CU
#define RPI (WAVES * 8)      // 64 rows per block-iteration
#define KIT (N / RPI)        // 32 k-iterations per pass
#define SCALE 0.08838834764831845f
#define LN_EPS 1e-5f
#define TAN_NORM_MAX 6.2f    // artanh(1-1e-5)=6.103; safe upper bound

// ---------- helpers ----------

__device__ __forceinline__ float artanh_clip(float a) {
  a = fminf(a, 1.0f - 1e-5f);
  return 0.5f * __logf((1.0f + a) / (1.0f - a));
}

__device__ __forceinline__ float logmap_scale(float n2) {
  float nc = fmaxf(sqrtf(n2), 1e-7f);
  return artanh_clip(nc) / nc;
}

// allreduce-sum across each 16-lane DPP row using ROW_ROR (pure VALU)
__device__ __forceinline__ float row16_sum(float x) {
  x += __int_as_float(__builtin_amdgcn_update_dpp(0, __float_as_int(x), 0x128, 0xF, 0xF, true)); // ror:8
  x += __int_as_float(__builtin_amdgcn_update_dpp(0, __float_as_int(x), 0x124, 0xF, 0xF, true)); // ror:4
  x += __int_as_float(__builtin_amdgcn_update_dpp(0, __float_as_int(x), 0x122, 0xF, 0xF, true)); // ror:2
  x += __int_as_float(__builtin_amdgcn_update_dpp(0, __float_as_int(x), 0x121, 0xF, 0xF, true)); // ror:1
  return x;
}

__device__ __forceinline__ float wave_allsum(float v) {
#pragma unroll
  for (int m = 1; m < 64; m <<= 1) v += __shfl_xor(v, m);
  return v;
}

__device__ __forceinline__ float dot128(const float* __restrict__ wrow,
                                        const float* __restrict__ x) {
  const float4* a = (const float4*)wrow;
  const float4* v = (const float4*)x;
  float s = 0.f;
#pragma unroll
  for (int j = 0; j < 32; ++j) {
    float4 u = a[j], b = v[j];
    s += u.x * b.x + u.y * b.y + u.z * b.z + u.w * b.w;
  }
  return s;
}

__device__ __forceinline__ float dot256(const float* __restrict__ wrow,
                                        const float* __restrict__ x) {
  const float4* a = (const float4*)wrow;
  const float4* v = (const float4*)x;
  float s = 0.f;
#pragma unroll
  for (int j = 0; j < 64; ++j) {
    float4 u = a[j], b = v[j];
    s += u.x * b.x + u.y * b.y + u.z * b.z + u.w * b.w;
  }
  return s;
}

// ---------- fused per-batch refiner: one block = one batch, all passes ----------

__global__ __launch_bounds__(TPB, 2) void fused_refiner(
    const float* __restrict__ demo, const float* __restrict__ rho,
    const float* __restrict__ seed_g_w, const float* __restrict__ seed_g_b,
    const float* __restrict__ seed_d_w, const float* __restrict__ pool_wq_w,
    const float* __restrict__ pool_wk_w, const float* __restrict__ pool_wv_w,
    const float* __restrict__ q_u_w, const float* __restrict__ q_g_w,
    const float* __restrict__ q_g_b, const float* __restrict__ kv_w,
    const float* __restrict__ mlp_w1, const float* __restrict__ mlp_b1,
    const float* __restrict__ mlp_w2, const float* __restrict__ mlp_b2,
    const float* __restrict__ ln_g, const float* __restrict__ ln_b,
    float* __restrict__ out) {
  const int b = blockIdx.x;
  const int tid = threadIdx.x;
  const int w = tid >> 6;
  const int lane = tid & 63;
  const int g = lane >> 4;   // row within wave's 4-row group
  const int il = lane & 15;  // 16 lanes per row

  __shared__ __align__(16) float s_rho[DG];
  __shared__ __align__(16) float s_x[DH];
  __shared__ __align__(16) float s_y[DH];
  __shared__ __align__(16) float s_h[HID];
  __shared__ __align__(16) float s_ut[DH];
  __shared__ __align__(16) float s_qseed[DH];
  __shared__ __align__(16) float s_qvec[DH];
  __shared__ __align__(16) float s_fold[WAVES][DH];
  __shared__ float s_l[WAVES];
  __shared__ float s_red[WAVES];
  __shared__ float s_Mb;

  // block-wide sum; all threads must call (inactive contribute 0)
  auto bsumAll = [&](float v) -> float {
    v = wave_allsum(v);
    if (lane == 0) s_red[w] = v;
    __syncthreads();
    float r = s_red[0] + s_red[1] + s_red[2] + s_red[3] +
              s_red[4] + s_red[5] + s_red[6] + s_red[7];
    __syncthreads();
    return r;
  };

  // shared epilogue: expmap -> logmap -> LN -> q -> qvec -> Mb
  auto ln_query = [&](float v) {
    float n2 = bsumAll(tid < DH ? v * v : 0.f);
    float u = 0.f, ut = 0.f;
    if (tid < DH) {
      float nc = fmaxf(sqrtf(n2), 1e-7f);
      u = v * (tanhf(nc) / nc);
    }
    float nu2 = bsumAll(tid < DH ? u * u : 0.f);
    if (tid < DH) {
      float nuc = fmaxf(sqrtf(nu2), 1e-7f);
      ut = u * (artanh_clip(nuc) / nuc);
    }
    float mu = bsumAll(tid < DH ? ut : 0.f) * (1.0f / DH);
    float d = ut - mu;
    float var = bsumAll(tid < DH ? d * d : 0.f) * (1.0f / DH);
    if (tid < DH) {
      float y = d * rsqrtf(var + LN_EPS) * ln_g[tid] + ln_b[tid];
      s_ut[tid] = y;
      s_x[tid] = y;
    }
    __syncthreads();
    if (tid < DH) {
      s_y[tid] = q_g_b[tid] + dot128(q_u_w + (size_t)tid * DH, s_x) +
                 dot256(q_g_w + (size_t)tid * DG, s_rho);
    }
    __syncthreads();
    float qp = 0.f;
    if (tid < DH) {
#pragma unroll 8
      for (int i = 0; i < DH; ++i) qp += kv_w[i * DH + tid] * s_y[i];
      s_qvec[tid] = qp;
    }
    float qn2 = bsumAll(tid < DH ? qp * qp : 0.f);
    if (tid == 0) s_Mb = SCALE * TAN_NORM_MAX * sqrtf(qn2);
    __syncthreads();
  };

  // ---- setup: q_seed, pooled-attention query, Mb ----
  if (tid < DG) s_rho[tid] = rho[(size_t)b * DG + tid];
  __syncthreads();
  if (tid < DH) {
    float qs = seed_g_b[tid] + dot256(seed_g_w + (size_t)tid * DG, s_rho);
    s_qseed[tid] = qs;
    s_x[tid] = qs;
  }
  __syncthreads();
  if (tid < DH) s_y[tid] = dot128(pool_wq_w + (size_t)tid * DH, s_x);
  __syncthreads();
  float qp0 = 0.f;
  if (tid < DH) {
#pragma unroll 8
    for (int i = 0; i < DH; ++i) qp0 += pool_wk_w[i * DH + tid] * s_y[i];
    s_qvec[tid] = qp0;
  }
  float qn2 = bsumAll(tid < DH ? qp0 * qp0 : 0.f);
  if (tid == 0) s_Mb = SCALE * TAN_NORM_MAX * sqrtf(qn2);
  __syncthreads();

  const float* demo_b = demo + (size_t)b * N * DH;

  for (int pass = 0; pass < 3; ++pass) {
    // ---- attention pass over all N rows ----
    // Fixed-bound softmax: Mb >= max score (Cauchy-Schwarz), plain exp sums.
    // wave w, iter k covers rows k*64 + w*8 + {g, g+4}; 16 lanes per row,
    // 8 floats per lane. 4-deep software pipeline: buffers for k..k+3 in
    // flight (16 outstanding float4 loads/wave = 128 KiB/CU), so the loop is
    // BW-bound, not round-trip-latency-bound.
    const float4 qv0 = *(const float4*)&s_qvec[il * 4];
    const float4 qv1 = *(const float4*)&s_qvec[64 + il * 4];
    const float Mb = s_Mb;
    const float* p = demo_b + (size_t)(w * 8 + g) * DH + il * 4;

    float lsum = 0.f;
    float4 accL = make_float4(0.f, 0.f, 0.f, 0.f);
    float4 accH = make_float4(0.f, 0.f, 0.f, 0.f);

    float4 A1[4], A2[4], B1[4], B2[4];
#pragma unroll
    for (int j = 0; j < 3; ++j) {
      const float* pj = p + (size_t)j * RPI * DH;
      A1[j] = *(const float4*)(pj);
      A2[j] = *(const float4*)(pj + 64);
      B1[j] = *(const float4*)(pj + 4 * DH);
      B2[j] = *(const float4*)(pj + 4 * DH + 64);
    }

    for (int kk = 0; kk < KIT; kk += 4) {
#pragma unroll
      for (int j = 0; j < 4; ++j) {
        const int k = kk + j;
        const int jn = (j + 3) & 3;  // buffer freed at iter k-1; holds k+3
        if (k + 3 < KIT) {
          const float* pn = p + (size_t)(k + 3) * RPI * DH;
          A1[jn] = *(const float4*)(pn);
          A2[jn] = *(const float4*)(pn + 64);
          B1[jn] = *(const float4*)(pn + 4 * DH);
          B2[jn] = *(const float4*)(pn + 4 * DH + 64);
        }
        float4 ca1 = A1[j], ca2 = A2[j], cb1 = B1[j], cb2 = B2[j];
        // group A (row k*64 + w*8 + g)
        {
          float dd = qv0.x * ca1.x + qv0.y * ca1.y + qv0.z * ca1.z + qv0.w * ca1.w +
                     qv1.x * ca2.x + qv1.y * ca2.y + qv1.z * ca2.z + qv1.w * ca2.w;
          float n2 = ca1.x * ca1.x + ca1.y * ca1.y + ca1.z * ca1.z + ca1.w * ca1.w +
                     ca2.x * ca2.x + ca2.y * ca2.y + ca2.z * ca2.z + ca2.w * ca2.w;
          dd = row16_sum(dd);
          n2 = row16_sum(n2);
          float tsv = logmap_scale(n2);
          float pw = __expf(dd * tsv * SCALE - Mb);
          lsum += pw;
          float c = pw * tsv;
          accL.x += c * ca1.x; accL.y += c * ca1.y; accL.z += c * ca1.z; accL.w += c * ca1.w;
          accH.x += c * ca2.x; accH.y += c * ca2.y; accH.z += c * ca2.z; accH.w += c * ca2.w;
        }
        // group B (row k*64 + w*8 + 4 + g)
        {
          float dd = qv0.x * cb1.x + qv0.y * cb1.y + qv0.z * cb1.z + qv0.w * cb1.w +
                     qv1.x * cb2.x + qv1.y * cb2.y + qv1.z * cb2.z + qv1.w * cb2.w;
          float n2 = cb1.x * cb1.x + cb1.y * cb1.y + cb1.z * cb1.z + cb1.w * cb1.w +
                     cb2.x * cb2.x + cb2.y * cb2.y + cb2.z * cb2.z + cb2.w * cb2.w;
          dd = row16_sum(dd);
          n2 = row16_sum(n2);
          float tsv = logmap_scale(n2);
          float pw = __expf(dd * tsv * SCALE - Mb);
          lsum += pw;
          float c = pw * tsv;
          accL.x += c * cb1.x; accL.y += c * cb1.y; accL.z += c * cb1.z; accL.w += c * cb1.w;
          accH.x += c * cb2.x; accH.y += c * cb2.y; accH.z += c * cb2.z; accH.w += c * cb2.w;
        }
      }
    }

    // fold the 4 g-groups within each wave (same d-slice, disjoint rows)
    accL.x += __shfl_xor(accL.x, 16); accL.x += __shfl_xor(accL.x, 32);
    accL.y += __shfl_xor(accL.y, 16); accL.y += __shfl_xor(accL.y, 32);
    accL.z += __shfl_xor(accL.z, 16); accL.z += __shfl_xor(accL.z, 32);
    accL.w += __shfl_xor(accL.w, 16); accL.w += __shfl_xor(accL.w, 32);
    accH.x += __shfl_xor(accH.x, 16); accH.x += __shfl_xor(accH.x, 32);
    accH.y += __shfl_xor(accH.y, 16); accH.y += __shfl_xor(accH.y, 32);
    accH.z += __shfl_xor(accH.z, 16); accH.z += __shfl_xor(accH.z, 32);
    accH.w += __shfl_xor(accH.w, 16); accH.w += __shfl_xor(accH.w, 32);
    lsum += __shfl_xor(lsum, 16); lsum += __shfl_xor(lsum, 32);
    if (g == 0) {
      *(float4*)&s_fold[w][il * 4] = accL;
      *(float4*)&s_fold[w][64 + il * 4] = accH;
      if (il == 0) s_l[w] = lsum;
    }
    __syncthreads();

    if (tid < DH) {
      float a = 0.f;
#pragma unroll
      for (int j = 0; j < WAVES; ++j) a += s_fold[j][tid];
      float L = s_l[0] + s_l[1] + s_l[2] + s_l[3] +
                s_l[4] + s_l[5] + s_l[6] + s_l[7];
      s_x[tid] = a / L;  // weighted value sum (= sum p*t / sum p)
    }
    __syncthreads();

    // ---- transition ----
    if (pass == 0) {
      if (tid < DH) s_y[tid] = dot128(pool_wv_w + (size_t)tid * DH, s_x);
      __syncthreads();
      float v = 0.f;
      if (tid < DH) v = s_qseed[tid] + dot128(seed_d_w + (size_t)tid * DH, s_y);
      ln_query(v);
    } else {
      if (tid < DH) s_y[tid] = dot128(kv_w + (size_t)tid * DH, s_x);
      __syncthreads();
      if (tid < HID) {
        float h = mlp_b1[tid] + dot128(mlp_w1 + (size_t)tid * DH, s_y);
        s_h[tid] = 0.5f * h * (1.0f + erff(h * 0.70710678118654752f));
      }
      __syncthreads();
      float v = 0.f;
      if (tid < DH)
        v = s_ut[tid] + mlp_b2[tid] + dot256(mlp_w2 + (size_t)tid * HID, s_h);
      if (pass == 2) {
        float n2 = bsumAll(tid < DH ? v * v : 0.f);
        if (tid < DH) {
          float nc = fmaxf(sqrtf(n2), 1e-7f);
          out[(size_t)b * DH + tid] = v * (tanhf(nc) / nc);
        }
      } else {
        ln_query(v);
      }
    }
  }
}

// ---------- launch ----------

extern "C" void kernel_launch(void* const* d_in, const int* in_sizes, int n_in,
                              void* d_out, int out_size, void* d_ws, size_t ws_size,
                              hipStream_t stream) {
  const float* demo      = (const float*)d_in[0];
  const float* rho       = (const float*)d_in[1];
  const float* seed_g_w  = (const float*)d_in[2];
  const float* seed_g_b  = (const float*)d_in[3];
  const float* seed_d_w  = (const float*)d_in[4];
  const float* pool_wq_w = (const float*)d_in[5];
  const float* pool_wk_w = (const float*)d_in[6];
  const float* pool_wv_w = (const float*)d_in[7];
  const float* q_u_w     = (const float*)d_in[8];
  const float* q_g_w     = (const float*)d_in[9];
  const float* q_g_b     = (const float*)d_in[10];
  const float* kv_w      = (const float*)d_in[11];
  const float* mlp_w1    = (const float*)d_in[12];
  const float* mlp_b1    = (const float*)d_in[13];
  const float* mlp_w2    = (const float*)d_in[14];
  const float* mlp_b2    = (const float*)d_in[15];
  const float* ln_g      = (const float*)d_in[16];
  const float* ln_b      = (const float*)d_in[17];
  float* out = (float*)d_out;
  (void)d_ws; (void)ws_size; (void)in_sizes; (void)n_in; (void)out_size;

  fused_refiner<<<B, TPB, 0, stream>>>(demo, rho, seed_g_w, seed_g_b, seed_d_w,
                                       pool_wq_w, pool_wk_w, pool_wv_w, q_u_w,
                                       q_g_w, q_g_b, kv_w, mlp_w1, mlp_b1,
                                       mlp_w2, mlp_b2, ln_g, ln_b, out);
}

// Round 4
// 519.340 us; speedup vs baseline: 1.0247x; 1.0247x over previous
//
#include <hip/hip_runtime.h>
#include <hip/hip_fp16.h>
#include <cstddef>
#include <cstdint>

#define B 256
#define N 2048
#define DH 128
#define DG 256
#define HID 256
#define WAVES 8
#define TPB (WAVES * 64)     // 512 threads, 8 waves, 1 block per CU
#define RPI (WAVES * 8)      // 64 rows per block-iteration
#define KIT (N / RPI)        // 32 k-iterations per pass
#define SCALE 0.08838834764831845f
#define LN_EPS 1e-5f
#define TAN_NORM_MAX 6.2f    // artanh(1-1e-5)=6.103; safe upper bound

// ---------- helpers ----------

__device__ __forceinline__ float artanh_clip(float a) {
  a = fminf(a, 1.0f - 1e-5f);
  return 0.5f * __logf((1.0f + a) / (1.0f - a));
}

__device__ __forceinline__ float logmap_scale(float n2) {
  float nc = fmaxf(sqrtf(n2), 1e-7f);
  return artanh_clip(nc) / nc;
}

// allreduce-sum across each 16-lane DPP row using ROW_ROR (pure VALU)
__device__ __forceinline__ float row16_sum(float x) {
  x += __int_as_float(__builtin_amdgcn_update_dpp(0, __float_as_int(x), 0x128, 0xF, 0xF, true)); // ror:8
  x += __int_as_float(__builtin_amdgcn_update_dpp(0, __float_as_int(x), 0x124, 0xF, 0xF, true)); // ror:4
  x += __int_as_float(__builtin_amdgcn_update_dpp(0, __float_as_int(x), 0x122, 0xF, 0xF, true)); // ror:2
  x += __int_as_float(__builtin_amdgcn_update_dpp(0, __float_as_int(x), 0x121, 0xF, 0xF, true)); // ror:1
  return x;
}

__device__ __forceinline__ float wave_allsum(float v) {
#pragma unroll
  for (int m = 1; m < 64; m <<= 1) v += __shfl_xor(v, m);
  return v;
}

__device__ __forceinline__ float dot128(const float* __restrict__ wrow,
                                        const float* __restrict__ x) {
  const float4* a = (const float4*)wrow;
  const float4* v = (const float4*)x;
  float s = 0.f;
#pragma unroll
  for (int j = 0; j < 32; ++j) {
    float4 u = a[j], b = v[j];
    s += u.x * b.x + u.y * b.y + u.z * b.z + u.w * b.w;
  }
  return s;
}

__device__ __forceinline__ float dot256(const float* __restrict__ wrow,
                                        const float* __restrict__ x) {
  const float4* a = (const float4*)wrow;
  const float4* v = (const float4*)x;
  float s = 0.f;
#pragma unroll
  for (int j = 0; j < 64; ++j) {
    float4 u = a[j], b = v[j];
    s += u.x * b.x + u.y * b.y + u.z * b.z + u.w * b.w;
  }
  return s;
}

// ---------- fused per-batch refiner: one block = one batch, all passes ----------
// Pass 0 reads fp32 demo (cold HBM), computes tangent rows y = ts*row, stores y
// as fp16 to a workspace cache (lane-swizzled layout, see below). Passes 1-2
// read the fp16 cache (128 MB, L3-resident): half the bytes, no logmap chain.
// All passes use a 4-deep register pipeline (static indices; launch_bounds
// gives >=256 VGPR cap so it does NOT spill like the 128-cap round-2 build).
//
// y-cache layout (self-consistent writer/reader): for each row, halves
// [il*8 .. il*8+7] hold row floats [il*4..il*4+3, 64+il*4..64+il*4+3].

__global__ __launch_bounds__(TPB, 1) void fused_refiner(
    const float* __restrict__ demo, const float* __restrict__ rho,
    const float* __restrict__ seed_g_w, const float* __restrict__ seed_g_b,
    const float* __restrict__ seed_d_w, const float* __restrict__ pool_wq_w,
    const float* __restrict__ pool_wk_w, const float* __restrict__ pool_wv_w,
    const float* __restrict__ q_u_w, const float* __restrict__ q_g_w,
    const float* __restrict__ q_g_b, const float* __restrict__ kv_w,
    const float* __restrict__ mlp_w1, const float* __restrict__ mlp_b1,
    const float* __restrict__ mlp_w2, const float* __restrict__ mlp_b2,
    const float* __restrict__ ln_g, const float* __restrict__ ln_b,
    __half* __restrict__ ycache, float* __restrict__ out) {
  const int b = blockIdx.x;
  const int tid = threadIdx.x;
  const int w = tid >> 6;
  const int lane = tid & 63;
  const int g = lane >> 4;   // row within wave's 4-row group
  const int il = lane & 15;  // 16 lanes per row

  __shared__ __align__(16) float s_rho[DG];
  __shared__ __align__(16) float s_x[DH];
  __shared__ __align__(16) float s_y[DH];
  __shared__ __align__(16) float s_h[HID];
  __shared__ __align__(16) float s_ut[DH];
  __shared__ __align__(16) float s_qseed[DH];
  __shared__ __align__(16) float s_qvec[DH];
  __shared__ __align__(16) float s_fold[WAVES][DH];
  __shared__ float s_l[WAVES];
  __shared__ float s_red[WAVES];
  __shared__ float s_Mb;

  // block-wide sum; all threads must call (inactive contribute 0)
  auto bsumAll = [&](float v) -> float {
    v = wave_allsum(v);
    if (lane == 0) s_red[w] = v;
    __syncthreads();
    float r = s_red[0] + s_red[1] + s_red[2] + s_red[3] +
              s_red[4] + s_red[5] + s_red[6] + s_red[7];
    __syncthreads();
    return r;
  };

  // shared epilogue: expmap -> logmap -> LN -> q -> qvec -> Mb
  auto ln_query = [&](float v) {
    float n2 = bsumAll(tid < DH ? v * v : 0.f);
    float u = 0.f, ut = 0.f;
    if (tid < DH) {
      float nc = fmaxf(sqrtf(n2), 1e-7f);
      u = v * (tanhf(nc) / nc);
    }
    float nu2 = bsumAll(tid < DH ? u * u : 0.f);
    if (tid < DH) {
      float nuc = fmaxf(sqrtf(nu2), 1e-7f);
      ut = u * (artanh_clip(nuc) / nuc);
    }
    float mu = bsumAll(tid < DH ? ut : 0.f) * (1.0f / DH);
    float d = ut - mu;
    float var = bsumAll(tid < DH ? d * d : 0.f) * (1.0f / DH);
    if (tid < DH) {
      float y = d * rsqrtf(var + LN_EPS) * ln_g[tid] + ln_b[tid];
      s_ut[tid] = y;
      s_x[tid] = y;
    }
    __syncthreads();
    if (tid < DH) {
      s_y[tid] = q_g_b[tid] + dot128(q_u_w + (size_t)tid * DH, s_x) +
                 dot256(q_g_w + (size_t)tid * DG, s_rho);
    }
    __syncthreads();
    float qp = 0.f;
    if (tid < DH) {
#pragma unroll 8
      for (int i = 0; i < DH; ++i) qp += kv_w[i * DH + tid] * s_y[i];
      s_qvec[tid] = qp;
    }
    float qn2 = bsumAll(tid < DH ? qp * qp : 0.f);
    if (tid == 0) s_Mb = SCALE * TAN_NORM_MAX * sqrtf(qn2);
    __syncthreads();
  };

  // ---- setup: q_seed, pooled-attention query, Mb ----
  if (tid < DG) s_rho[tid] = rho[(size_t)b * DG + tid];
  __syncthreads();
  if (tid < DH) {
    float qs = seed_g_b[tid] + dot256(seed_g_w + (size_t)tid * DG, s_rho);
    s_qseed[tid] = qs;
    s_x[tid] = qs;
  }
  __syncthreads();
  if (tid < DH) s_y[tid] = dot128(pool_wq_w + (size_t)tid * DH, s_x);
  __syncthreads();
  float qp0 = 0.f;
  if (tid < DH) {
#pragma unroll 8
    for (int i = 0; i < DH; ++i) qp0 += pool_wk_w[i * DH + tid] * s_y[i];
    s_qvec[tid] = qp0;
  }
  float qn2 = bsumAll(tid < DH ? qp0 * qp0 : 0.f);
  if (tid == 0) s_Mb = SCALE * TAN_NORM_MAX * sqrtf(qn2);
  __syncthreads();

  const float* demo_b = demo + (size_t)b * N * DH;
  __half* yc_b = ycache + (size_t)b * N * DH;

  for (int pass = 0; pass < 3; ++pass) {
    const float4 qv0 = *(const float4*)&s_qvec[il * 4];
    const float4 qv1 = *(const float4*)&s_qvec[64 + il * 4];
    const float Mb = s_Mb;

    float lsum = 0.f;
    float4 accL = make_float4(0.f, 0.f, 0.f, 0.f);
    float4 accH = make_float4(0.f, 0.f, 0.f, 0.f);

    if (pass == 0) {
      // ---- fp32 source pass: compute ts, emit fp16 y-cache ----
      const float* p = demo_b + (size_t)(w * 8 + g) * DH + il * 4;
      __half* yw = yc_b + (size_t)(w * 8 + g) * DH + (size_t)il * 8;

      float4 A1[4], A2[4], B1[4], B2[4];
#pragma unroll
      for (int j = 0; j < 3; ++j) {
        const float* pj = p + (size_t)j * RPI * DH;
        A1[j] = *(const float4*)(pj);
        A2[j] = *(const float4*)(pj + 64);
        B1[j] = *(const float4*)(pj + 4 * DH);
        B2[j] = *(const float4*)(pj + 4 * DH + 64);
      }

      for (int kk = 0; kk < KIT; kk += 4) {
#pragma unroll
        for (int j = 0; j < 4; ++j) {
          const int k = kk + j;
          const int jn = (j + 3) & 3;  // slot freed at k-1; receives k+3
          if (k + 3 < KIT) {
            const float* pn = p + (size_t)(k + 3) * RPI * DH;
            A1[jn] = *(const float4*)(pn);
            A2[jn] = *(const float4*)(pn + 64);
            B1[jn] = *(const float4*)(pn + 4 * DH);
            B2[jn] = *(const float4*)(pn + 4 * DH + 64);
          }
          float4 ca1 = A1[j], ca2 = A2[j], cb1 = B1[j], cb2 = B2[j];
          // group A (row k*64 + w*8 + g)
          {
            float dd = qv0.x * ca1.x + qv0.y * ca1.y + qv0.z * ca1.z + qv0.w * ca1.w +
                       qv1.x * ca2.x + qv1.y * ca2.y + qv1.z * ca2.z + qv1.w * ca2.w;
            float n2 = ca1.x * ca1.x + ca1.y * ca1.y + ca1.z * ca1.z + ca1.w * ca1.w +
                       ca2.x * ca2.x + ca2.y * ca2.y + ca2.z * ca2.z + ca2.w * ca2.w;
            dd = row16_sum(dd);
            n2 = row16_sum(n2);
            float tsv = logmap_scale(n2);
            float4 y1 = make_float4(tsv * ca1.x, tsv * ca1.y, tsv * ca1.z, tsv * ca1.w);
            float4 y2 = make_float4(tsv * ca2.x, tsv * ca2.y, tsv * ca2.z, tsv * ca2.w);
            __half2 h01 = __float22half2_rn(make_float2(y1.x, y1.y));
            __half2 h23 = __float22half2_rn(make_float2(y1.z, y1.w));
            __half2 h45 = __float22half2_rn(make_float2(y2.x, y2.y));
            __half2 h67 = __float22half2_rn(make_float2(y2.z, y2.w));
            uint4 pk;
            pk.x = *(const unsigned*)&h01; pk.y = *(const unsigned*)&h23;
            pk.z = *(const unsigned*)&h45; pk.w = *(const unsigned*)&h67;
            *(uint4*)(yw + (size_t)k * RPI * DH) = pk;
            float pw = __expf(dd * tsv * SCALE - Mb);
            lsum += pw;
            accL.x += pw * y1.x; accL.y += pw * y1.y; accL.z += pw * y1.z; accL.w += pw * y1.w;
            accH.x += pw * y2.x; accH.y += pw * y2.y; accH.z += pw * y2.z; accH.w += pw * y2.w;
          }
          // group B (row k*64 + w*8 + 4 + g)
          {
            float dd = qv0.x * cb1.x + qv0.y * cb1.y + qv0.z * cb1.z + qv0.w * cb1.w +
                       qv1.x * cb2.x + qv1.y * cb2.y + qv1.z * cb2.z + qv1.w * cb2.w;
            float n2 = cb1.x * cb1.x + cb1.y * cb1.y + cb1.z * cb1.z + cb1.w * cb1.w +
                       cb2.x * cb2.x + cb2.y * cb2.y + cb2.z * cb2.z + cb2.w * cb2.w;
            dd = row16_sum(dd);
            n2 = row16_sum(n2);
            float tsv = logmap_scale(n2);
            float4 y1 = make_float4(tsv * cb1.x, tsv * cb1.y, tsv * cb1.z, tsv * cb1.w);
            float4 y2 = make_float4(tsv * cb2.x, tsv * cb2.y, tsv * cb2.z, tsv * cb2.w);
            __half2 h01 = __float22half2_rn(make_float2(y1.x, y1.y));
            __half2 h23 = __float22half2_rn(make_float2(y1.z, y1.w));
            __half2 h45 = __float22half2_rn(make_float2(y2.x, y2.y));
            __half2 h67 = __float22half2_rn(make_float2(y2.z, y2.w));
            uint4 pk;
            pk.x = *(const unsigned*)&h01; pk.y = *(const unsigned*)&h23;
            pk.z = *(const unsigned*)&h45; pk.w = *(const unsigned*)&h67;
            *(uint4*)(yw + (size_t)k * RPI * DH + 4 * DH) = pk;
            float pw = __expf(dd * tsv * SCALE - Mb);
            lsum += pw;
            accL.x += pw * y1.x; accL.y += pw * y1.y; accL.z += pw * y1.z; accL.w += pw * y1.w;
            accH.x += pw * y2.x; accH.y += pw * y2.y; accH.z += pw * y2.z; accH.w += pw * y2.w;
          }
        }
      }
    } else {
      // ---- fp16 y-cache pass: no logmap, half the bytes, L3-resident ----
      const __half* yr = yc_b + (size_t)(w * 8 + g) * DH + (size_t)il * 8;

      uint4 YA[4], YB[4];
#pragma unroll
      for (int j = 0; j < 3; ++j) {
        YA[j] = *(const uint4*)(yr + (size_t)j * RPI * DH);
        YB[j] = *(const uint4*)(yr + (size_t)j * RPI * DH + 4 * DH);
      }

      for (int kk = 0; kk < KIT; kk += 4) {
#pragma unroll
        for (int j = 0; j < 4; ++j) {
          const int k = kk + j;
          const int jn = (j + 3) & 3;
          if (k + 3 < KIT) {
            YA[jn] = *(const uint4*)(yr + (size_t)(k + 3) * RPI * DH);
            YB[jn] = *(const uint4*)(yr + (size_t)(k + 3) * RPI * DH + 4 * DH);
          }
          // group A
          {
            uint4 pk = YA[j];
            float2 f0 = __half22float2(*(const __half2*)&pk.x);
            float2 f1 = __half22float2(*(const __half2*)&pk.y);
            float2 f2 = __half22float2(*(const __half2*)&pk.z);
            float2 f3 = __half22float2(*(const __half2*)&pk.w);
            float dd = qv0.x * f0.x + qv0.y * f0.y + qv0.z * f1.x + qv0.w * f1.y +
                       qv1.x * f2.x + qv1.y * f2.y + qv1.z * f3.x + qv1.w * f3.y;
            dd = row16_sum(dd);
            float pw = __expf(dd * SCALE - Mb);
            lsum += pw;
            accL.x += pw * f0.x; accL.y += pw * f0.y; accL.z += pw * f1.x; accL.w += pw * f1.y;
            accH.x += pw * f2.x; accH.y += pw * f2.y; accH.z += pw * f3.x; accH.w += pw * f3.y;
          }
          // group B
          {
            uint4 pk = YB[j];
            float2 f0 = __half22float2(*(const __half2*)&pk.x);
            float2 f1 = __half22float2(*(const __half2*)&pk.y);
            float2 f2 = __half22float2(*(const __half2*)&pk.z);
            float2 f3 = __half22float2(*(const __half2*)&pk.w);
            float dd = qv0.x * f0.x + qv0.y * f0.y + qv0.z * f1.x + qv0.w * f1.y +
                       qv1.x * f2.x + qv1.y * f2.y + qv1.z * f3.x + qv1.w * f3.y;
            dd = row16_sum(dd);
            float pw = __expf(dd * SCALE - Mb);
            lsum += pw;
            accL.x += pw * f0.x; accL.y += pw * f0.y; accL.z += pw * f1.x; accL.w += pw * f1.y;
            accH.x += pw * f2.x; accH.y += pw * f2.y; accH.z += pw * f3.x; accH.w += pw * f3.y;
          }
        }
      }
    }

    // fold the 4 g-groups within each wave (same d-slice, disjoint rows)
    accL.x += __shfl_xor(accL.x, 16); accL.x += __shfl_xor(accL.x, 32);
    accL.y += __shfl_xor(accL.y, 16); accL.y += __shfl_xor(accL.y, 32);
    accL.z += __shfl_xor(accL.z, 16); accL.z += __shfl_xor(accL.z, 32);
    accL.w += __shfl_xor(accL.w, 16); accL.w += __shfl_xor(accL.w, 32);
    accH.x += __shfl_xor(accH.x, 16); accH.x += __shfl_xor(accH.x, 32);
    accH.y += __shfl_xor(accH.y, 16); accH.y += __shfl_xor(accH.y, 32);
    accH.z += __shfl_xor(accH.z, 16); accH.z += __shfl_xor(accH.z, 32);
    accH.w += __shfl_xor(accH.w, 16); accH.w += __shfl_xor(accH.w, 32);
    lsum += __shfl_xor(lsum, 16); lsum += __shfl_xor(lsum, 32);
    if (g == 0) {
      *(float4*)&s_fold[w][il * 4] = accL;
      *(float4*)&s_fold[w][64 + il * 4] = accH;
      if (il == 0) s_l[w] = lsum;
    }
    __syncthreads();

    if (tid < DH) {
      float a = 0.f;
#pragma unroll
      for (int j = 0; j < WAVES; ++j) a += s_fold[j][tid];
      float L = s_l[0] + s_l[1] + s_l[2] + s_l[3] +
                s_l[4] + s_l[5] + s_l[6] + s_l[7];
      s_x[tid] = a / L;  // weighted tangent value (= sum p*y / sum p)
    }
    __syncthreads();

    // ---- transition ----
    if (pass == 0) {
      if (tid < DH) s_y[tid] = dot128(pool_wv_w + (size_t)tid * DH, s_x);
      __syncthreads();
      float v = 0.f;
      if (tid < DH) v = s_qseed[tid] + dot128(seed_d_w + (size_t)tid * DH, s_y);
      ln_query(v);
    } else {
      if (tid < DH) s_y[tid] = dot128(kv_w + (size_t)tid * DH, s_x);
      __syncthreads();
      if (tid < HID) {
        float h = mlp_b1[tid] + dot128(mlp_w1 + (size_t)tid * DH, s_y);
        s_h[tid] = 0.5f * h * (1.0f + erff(h * 0.70710678118654752f));
      }
      __syncthreads();
      float v = 0.f;
      if (tid < DH)
        v = s_ut[tid] + mlp_b2[tid] + dot256(mlp_w2 + (size_t)tid * HID, s_h);
      if (pass == 2) {
        float n2 = bsumAll(tid < DH ? v * v : 0.f);
        if (tid < DH) {
          float nc = fmaxf(sqrtf(n2), 1e-7f);
          out[(size_t)b * DH + tid] = v * (tanhf(nc) / nc);
        }
      } else {
        ln_query(v);
      }
    }
  }
}

// ---------- launch ----------

extern "C" void kernel_launch(void* const* d_in, const int* in_sizes, int n_in,
                              void* d_out, int out_size, void* d_ws, size_t ws_size,
                              hipStream_t stream) {
  const float* demo      = (const float*)d_in[0];
  const float* rho       = (const float*)d_in[1];
  const float* seed_g_w  = (const float*)d_in[2];
  const float* seed_g_b  = (const float*)d_in[3];
  const float* seed_d_w  = (const float*)d_in[4];
  const float* pool_wq_w = (const float*)d_in[5];
  const float* pool_wk_w = (const float*)d_in[6];
  const float* pool_wv_w = (const float*)d_in[7];
  const float* q_u_w     = (const float*)d_in[8];
  const float* q_g_w     = (const float*)d_in[9];
  const float* q_g_b     = (const float*)d_in[10];
  const float* kv_w      = (const float*)d_in[11];
  const float* mlp_w1    = (const float*)d_in[12];
  const float* mlp_b1    = (const float*)d_in[13];
  const float* mlp_w2    = (const float*)d_in[14];
  const float* mlp_b2    = (const float*)d_in[15];
  const float* ln_g      = (const float*)d_in[16];
  const float* ln_b      = (const float*)d_in[17];
  float* out = (float*)d_out;
  __half* ycache = (__half*)d_ws;  // B*N*DH halves = 128 MB
  (void)ws_size; (void)in_sizes; (void)n_in; (void)out_size;

  fused_refiner<<<B, TPB, 0, stream>>>(demo, rho, seed_g_w, seed_g_b, seed_d_w,
                                       pool_wq_w, pool_wk_w, pool_wv_w, q_u_w,
                                       q_g_w, q_g_b, kv_w, mlp_w1, mlp_b1,
                                       mlp_w2, mlp_b2, ln_g, ln_b, ycache, out);
}